// Round 14
// baseline (2471.892 us; speedup 1.0000x reference)
//
#include <hip/hip_runtime.h>
#include <math.h>

#define D 64
#define S 4

// ---------------- workspace layout (float offsets) ----------------
#define WS_KEYS 0      // keys[S][D]
#define WS_ST   256    // st_norm[S]
#define WS_SUMS 260    // uw_sums[S] (atomic, zeroed each launch)
#define WS_LW   264    // last_writer[S] (int, -1 init)
#define WS_OUT1 272    // out1[D] (16B aligned)
#define WS_WCT  512    // wct[c][k][i] = Wq[(c*16+i)][k]  (4 chunks x 64 k x 16 dims)

__global__ void k_prep(const float* __restrict__ slots,
                       const float* __restrict__ ss,
                       const float* __restrict__ Wk,
                       const float* __restrict__ bk,
                       const float* __restrict__ Wq,
                       float* __restrict__ ws) {
  int d = threadIdx.x;  // 64 threads
  __shared__ float sl[S][D];
  for (int s = 0; s < S; ++s) sl[s][d] = slots[s * D + d];
  __syncthreads();
  float bkd = bk[d];
  for (int s = 0; s < S; ++s) {
    float acc = bkd;
    for (int k = 0; k < D; ++k) acc = fmaf(sl[s][k], Wk[d * D + k], acc);
    ws[WS_KEYS + s * D + d] = tanhf(acc);
  }
  // W chunk-transpose: wct[((c*64)+k)*16 + i] = Wq[(c*16+i)*64 + k]
  {
    int c = d >> 4, i = d & 15;
    for (int k = 0; k < D; ++k)
      ws[WS_WCT + ((c * 64 + k) * 16 + i)] = Wq[d * D + k];
  }
  if (d < S) {
    ws[WS_SUMS + d] = 0.f;
    ((int*)ws)[WS_LW + d] = -1;
  }
  if (d == 0) {
    float st[S]; float tot = 0.f;
    for (int s = 0; s < S; ++s) {
      float x = ss[s];
      float sp = log1pf(expf(-fabsf(x))) + fmaxf(x, 0.f);  // softplus
      st[s] = sp; tot += sp;
    }
    for (int s = 0; s < S; ++s) ws[WS_ST + s] = st[s] / tot;
  }
}

// NOTE: macro params must not collide with .x/.y/.z/.w member names
#define FMA4(A_, XS_, W_) \
  A_.x = fmaf(XS_, W_.x, A_.x); A_.y = fmaf(XS_, W_.y, A_.y); \
  A_.z = fmaf(XS_, W_.z, A_.z); A_.w = fmaf(XS_, W_.w, A_.w);

#define TANH1(V_) fmaf(-2.f, __builtin_amdgcn_rcpf(__expf(2.f * (V_)) + 1.f), 1.f)
#define TANH4(A_) { A_.x = TANH1(A_.x); A_.y = TANH1(A_.y); A_.z = TANH1(A_.z); A_.w = TANH1(A_.w); }

#define DOT4ACC(P_, A_, K_) \
  P_ = fmaf(A_.x, K_.x, P_); P_ = fmaf(A_.y, K_.y, P_); \
  P_ = fmaf(A_.z, K_.z, P_); P_ = fmaf(A_.w, K_.w, P_);

// one k-scalar for BOTH rows: 4 W float4s (uniform s_load) feed 8 FMA4s
#define QK2(XSA_, XSB_, KI_) { \
  float4 w0 = wb[(KI_) * 4 + 0], w1 = wb[(KI_) * 4 + 1]; \
  float4 w2 = wb[(KI_) * 4 + 2], w3 = wb[(KI_) * 4 + 3]; \
  FMA4(CA0, XSA_, w0) FMA4(CA1, XSA_, w1) FMA4(CA2, XSA_, w2) FMA4(CA3, XSA_, w3) \
  FMA4(CB0, XSB_, w0) FMA4(CB1, XSB_, w1) FMA4(CB2, XSB_, w2) FMA4(CB3, XSB_, w3) }

// one x-float4 (4 consecutive k) for both rows
#define QK8(XVA_, XVB_, KB_) \
  QK2(XVA_.x, XVB_.x, KB_)       QK2(XVA_.y, XVB_.y, (KB_) + 1) \
  QK2(XVA_.z, XVB_.z, (KB_) + 2) QK2(XVA_.w, XVB_.w, (KB_) + 3)

// 2 rows/lane interleaved through the same W pass (R10 structure, proven 116us
// at VGPR=104 / 4 waves/SIMD). True live state ~70 VGPR (keys/bq/W in SGPRs);
// min-waves=6 caps allocation at 85 -> 6 waves/SIMD for +50% latency hiding.
// B == gridDim.x * 512 exactly -> no guards.
__launch_bounds__(256, 6)
__global__ void k_main(const float* __restrict__ item,
                       const float* __restrict__ wct,   // ws+WS_WCT
                       const float* __restrict__ keys,  // ws+WS_KEYS
                       const float* __restrict__ st4,   // ws+WS_ST
                       const float* __restrict__ bq,
                       float* red,                      // ws (atomics)
                       float* __restrict__ slot_weights,
                       float* __restrict__ selected,
                       int B) {
  __shared__ float red_sum[4][S];
  __shared__ int   red_lw[4][S];

  int t = threadIdx.x;
  long rA = (long)blockIdx.x * 512 + t;
  long rB = rA + 256;

  const float4* rowA = (const float4*)(item + rA * D);
  const float4* rowB = (const float4*)(item + rB * D);

  const float4* bq4 = (const float4*)bq;     // uniform
  const float4* kr  = (const float4*)keys;   // uniform

  float SA0 = 0.f, SA1 = 0.f, SA2 = 0.f, SA3 = 0.f;
  float SB0 = 0.f, SB1 = 0.f, SB2 = 0.f, SB3 = 0.f;

  #pragma unroll 1
  for (int c = 0; c < 4; ++c) {
    const float4* wb = (const float4*)wct + c * 256;   // 4KB slab, uniform
    float4 CA0 = bq4[c * 4 + 0], CA1 = bq4[c * 4 + 1];
    float4 CA2 = bq4[c * 4 + 2], CA3 = bq4[c * 4 + 3];
    float4 CB0 = CA0, CB1 = CA1, CB2 = CA2, CB3 = CA3;

    #pragma unroll
    for (int kq = 0; kq < 16; ++kq) {
      float4 xa = rowA[kq];
      float4 xb = rowB[kq];
      QK8(xa, xb, kq * 4)
    }

    TANH4(CA0) TANH4(CA1) TANH4(CA2) TANH4(CA3)
    TANH4(CB0) TANH4(CB1) TANH4(CB2) TANH4(CB3)

    // sims over this chunk's 16 dims (sequential-d order preserved)
    {
      const float4* k0 = kr + 0 * 16 + c * 4;
      DOT4ACC(SA0, CA0, k0[0]) DOT4ACC(SA0, CA1, k0[1]) DOT4ACC(SA0, CA2, k0[2]) DOT4ACC(SA0, CA3, k0[3])
      DOT4ACC(SB0, CB0, k0[0]) DOT4ACC(SB0, CB1, k0[1]) DOT4ACC(SB0, CB2, k0[2]) DOT4ACC(SB0, CB3, k0[3])
      const float4* k1 = kr + 1 * 16 + c * 4;
      DOT4ACC(SA1, CA0, k1[0]) DOT4ACC(SA1, CA1, k1[1]) DOT4ACC(SA1, CA2, k1[2]) DOT4ACC(SA1, CA3, k1[3])
      DOT4ACC(SB1, CB0, k1[0]) DOT4ACC(SB1, CB1, k1[1]) DOT4ACC(SB1, CB2, k1[2]) DOT4ACC(SB1, CB3, k1[3])
      const float4* k2 = kr + 2 * 16 + c * 4;
      DOT4ACC(SA2, CA0, k2[0]) DOT4ACC(SA2, CA1, k2[1]) DOT4ACC(SA2, CA2, k2[2]) DOT4ACC(SA2, CA3, k2[3])
      DOT4ACC(SB2, CB0, k2[0]) DOT4ACC(SB2, CB1, k2[1]) DOT4ACC(SB2, CB2, k2[2]) DOT4ACC(SB2, CB3, k2[3])
      const float4* k3 = kr + 3 * 16 + c * 4;
      DOT4ACC(SA3, CA0, k3[0]) DOT4ACC(SA3, CA1, k3[1]) DOT4ACC(SA3, CA2, k3[2]) DOT4ACC(SA3, CA3, k3[3])
      DOT4ACC(SB3, CB0, k3[0]) DOT4ACC(SB3, CB1, k3[1]) DOT4ACC(SB3, CB2, k3[2]) DOT4ACC(SB3, CB3, k3[3])
    }
  }

  float s0 = st4[0], s1 = st4[1], s2 = st4[2], s3 = st4[3];

  float uA[S], uB[S];
  int selA = 0, selB = 0;
  {
    float m = fmaxf(fmaxf(SA0, SA1), fmaxf(SA2, SA3));
    float e0 = expf(SA0 - m), e1 = expf(SA1 - m);
    float e2 = expf(SA2 - m), e3 = expf(SA3 - m);
    float se = e0 + e1 + e2 + e3;
    float w0 = e0 / se, w1 = e1 / se, w2 = e2 / se, w3 = e3 / se;
    *(float4*)(slot_weights + rA * S) = make_float4(w0, w1, w2, w3);
    uA[0] = w0 * s0; uA[1] = w1 * s1; uA[2] = w2 * s2; uA[3] = w3 * s3;
    float us = uA[0] + uA[1] + uA[2] + uA[3];
    uA[0] /= us; uA[1] /= us; uA[2] /= us; uA[3] /= us;
    float best = uA[0];
    if (uA[1] > best) { best = uA[1]; selA = 1; }
    if (uA[2] > best) { best = uA[2]; selA = 2; }
    if (uA[3] > best) { best = uA[3]; selA = 3; }
    selected[rA] = (float)selA;
  }
  {
    float m = fmaxf(fmaxf(SB0, SB1), fmaxf(SB2, SB3));
    float e0 = expf(SB0 - m), e1 = expf(SB1 - m);
    float e2 = expf(SB2 - m), e3 = expf(SB3 - m);
    float se = e0 + e1 + e2 + e3;
    float w0 = e0 / se, w1 = e1 / se, w2 = e2 / se, w3 = e3 / se;
    *(float4*)(slot_weights + rB * S) = make_float4(w0, w1, w2, w3);
    uB[0] = w0 * s0; uB[1] = w1 * s1; uB[2] = w2 * s2; uB[3] = w3 * s3;
    float us = uB[0] + uB[1] + uB[2] + uB[3];
    uB[0] /= us; uB[1] /= us; uB[2] /= us; uB[3] /= us;
    float best = uB[0];
    if (uB[1] > best) { best = uB[1]; selB = 1; }
    if (uB[2] > best) { best = uB[2]; selB = 2; }
    if (uB[3] > best) { best = uB[3]; selB = 3; }
    selected[rB] = (float)selB;
  }

  // ---- block reduction: uw sums (add) and last-writer (max) ----
  float r[S]; int l[S];
  #pragma unroll
  for (int s = 0; s < S; ++s) {
    r[s] = uA[s] + uB[s];
    l[s] = (selB == s) ? (int)rB : ((selA == s) ? (int)rA : -1);  // rB > rA
  }
  #pragma unroll
  for (int off = 32; off > 0; off >>= 1) {
    #pragma unroll
    for (int s = 0; s < S; ++s) {
      r[s] += __shfl_down(r[s], off);
      int m = __shfl_down(l[s], off);
      l[s] = l[s] > m ? l[s] : m;
    }
  }
  int lane = t & 63, wid = t >> 6;
  if (lane == 0) {
    #pragma unroll
    for (int s = 0; s < S; ++s) { red_sum[wid][s] = r[s]; red_lw[wid][s] = l[s]; }
  }
  __syncthreads();
  if (t < S) {
    float tot = red_sum[0][t] + red_sum[1][t] + red_sum[2][t] + red_sum[3][t];
    atomicAdd(&red[WS_SUMS + t], tot);
    int lm = red_lw[0][t];
    if (red_lw[1][t] > lm) lm = red_lw[1][t];
    if (red_lw[2][t] > lm) lm = red_lw[2][t];
    if (red_lw[3][t] > lm) lm = red_lw[3][t];
    atomicMax((int*)red + WS_LW + t, lm);
  }
}

__global__ void k_final(const float* __restrict__ item,
                        const float* __restrict__ slots,
                        const float* __restrict__ usage,
                        const float* __restrict__ Wv,
                        const float* __restrict__ bv,
                        float* ws,
                        float* __restrict__ out_ns,
                        float* __restrict__ out_nu,
                        int B) {
  int d = threadIdx.x;  // 64 threads
  __shared__ float mean[D];
  const int* lw = (const int*)ws + WS_LW;
  float nsv[S];
  for (int s = 0; s < S; ++s) {
    int w = lw[s];
    float v = (w >= 0) ? item[(size_t)w * D + d] : slots[s * D + d];
    nsv[s] = v;
    out_ns[s * D + d] = v;
  }
  mean[d] = (nsv[0] + nsv[1] + nsv[2] + nsv[3]) * 0.25f;
  __syncthreads();
  float acc = bv[d];
  for (int k = 0; k < D; ++k) acc = fmaf(mean[k], Wv[d * D + k], acc);
  ws[WS_OUT1 + d] = tanhf(acc);
  if (d < S) out_nu[d] = usage[d] * 0.9f + ws[WS_SUMS + d] / (float)B;
}

__global__ void k_bcast(const float* __restrict__ ws,
                        float4* __restrict__ out, long n4) {
  __shared__ float4 o4[16];
  if (threadIdx.x < 16) o4[threadIdx.x] = ((const float4*)(ws + WS_OUT1))[threadIdx.x];
  __syncthreads();
  long i = (long)blockIdx.x * blockDim.x + threadIdx.x;
  long stride = (long)gridDim.x * blockDim.x;
  for (; i < n4; i += stride) out[i] = o4[i & 15];
}

extern "C" void kernel_launch(void* const* d_in, const int* in_sizes, int n_in,
                              void* d_out, int out_size, void* d_ws, size_t ws_size,
                              hipStream_t stream) {
  const float* item  = (const float*)d_in[0];
  const float* slots = (const float*)d_in[1];
  const float* ss    = (const float*)d_in[2];
  const float* usage = (const float*)d_in[3];
  const float* Wq    = (const float*)d_in[4];
  const float* bq    = (const float*)d_in[5];
  const float* Wk    = (const float*)d_in[6];
  const float* bk    = (const float*)d_in[7];
  const float* Wv    = (const float*)d_in[8];
  const float* bv    = (const float*)d_in[9];
  int B = in_sizes[0] / D;
  float* ws = (float*)d_ws;

  float* out_output       = (float*)d_out;
  float* out_new_slots    = out_output + (size_t)B * D;
  float* out_new_usage    = out_new_slots + S * D;
  float* out_selected     = out_new_usage + S;
  float* out_slot_weights = out_selected + B;

  k_prep<<<1, 64, 0, stream>>>(slots, ss, Wk, bk, Wq, ws);
  k_main<<<B / 512, 256, 0, stream>>>(
      item, ws + WS_WCT, ws + WS_KEYS, ws + WS_ST, bq, ws,
      out_slot_weights, out_selected, B);
  k_final<<<1, 64, 0, stream>>>(item, slots, usage, Wv, bv, ws,
                                out_new_slots, out_new_usage, B);
  long n4 = (long)B * D / 4;
  k_bcast<<<2048, 256, 0, stream>>>(ws, (float4*)out_output, n4);
}

// Round 15
// 127.476 us; speedup vs baseline: 19.3911x; 19.3911x over previous
//
#include <hip/hip_runtime.h>
#include <math.h>

#define D 64
#define S 4

// ---------------- workspace layout (float offsets) ----------------
#define WS_KEYS 0      // keys[S][D]
#define WS_ST   256    // st_norm[S]
#define WS_SUMS 260    // uw_sums[S] (atomic, zeroed each launch)
#define WS_LW   264    // last_writer[S] (int, -1 init)
#define WS_OUT1 272    // out1[D] (16B aligned)
#define WS_WCT  512    // wct[c][k][i] = Wq[(c*32+i)][k]  (2 chunks x 64 k x 32 dims)

__global__ void k_prep(const float* __restrict__ slots,
                       const float* __restrict__ ss,
                       const float* __restrict__ Wk,
                       const float* __restrict__ bk,
                       const float* __restrict__ Wq,
                       float* __restrict__ ws) {
  int d = threadIdx.x;  // 64 threads
  __shared__ float sl[S][D];
  for (int s = 0; s < S; ++s) sl[s][d] = slots[s * D + d];
  __syncthreads();
  float bkd = bk[d];
  for (int s = 0; s < S; ++s) {
    float acc = bkd;
    for (int k = 0; k < D; ++k) acc = fmaf(sl[s][k], Wk[d * D + k], acc);
    ws[WS_KEYS + s * D + d] = tanhf(acc);
  }
  // W chunk-transpose (32-dim chunks): wct[((c*64)+k)*32 + i] = Wq[(c*32+i)*64 + k]
  {
    int c = d >> 5, i = d & 31;
    for (int k = 0; k < D; ++k)
      ws[WS_WCT + ((c * 64 + k) * 32 + i)] = Wq[d * D + k];
  }
  if (d < S) {
    ws[WS_SUMS + d] = 0.f;
    ((int*)ws)[WS_LW + d] = -1;
  }
  if (d == 0) {
    float st[S]; float tot = 0.f;
    for (int s = 0; s < S; ++s) {
      float x = ss[s];
      float sp = log1pf(expf(-fabsf(x))) + fmaxf(x, 0.f);  // softplus
      st[s] = sp; tot += sp;
    }
    for (int s = 0; s < S; ++s) ws[WS_ST + s] = st[s] / tot;
  }
}

// NOTE: macro params must not collide with .x/.y/.z/.w member names
#define FMA4(A_, XS_, W_) \
  A_.x = fmaf(XS_, W_.x, A_.x); A_.y = fmaf(XS_, W_.y, A_.y); \
  A_.z = fmaf(XS_, W_.z, A_.z); A_.w = fmaf(XS_, W_.w, A_.w);

#define TANH1(V_) fmaf(-2.f, __builtin_amdgcn_rcpf(__expf(2.f * (V_)) + 1.f), 1.f)
#define TANH4(A_) { A_.x = TANH1(A_.x); A_.y = TANH1(A_.y); A_.z = TANH1(A_.z); A_.w = TANH1(A_.w); }

#define DOT4ACC(P_, A_, K_) \
  P_ = fmaf(A_.x, K_.x, P_); P_ = fmaf(A_.y, K_.y, P_); \
  P_ = fmaf(A_.z, K_.z, P_); P_ = fmaf(A_.w, K_.w, P_);

// one k-scalar for BOTH rows over 32 dims: 8 W float4s feed 16 FMA4s
#define QK2(XSA_, XSB_, KI_) { \
  float4 w0 = wb[(KI_) * 8 + 0], w1 = wb[(KI_) * 8 + 1]; \
  float4 w2 = wb[(KI_) * 8 + 2], w3 = wb[(KI_) * 8 + 3]; \
  float4 w4 = wb[(KI_) * 8 + 4], w5 = wb[(KI_) * 8 + 5]; \
  float4 w6 = wb[(KI_) * 8 + 6], w7 = wb[(KI_) * 8 + 7]; \
  FMA4(CA0, XSA_, w0) FMA4(CA1, XSA_, w1) FMA4(CA2, XSA_, w2) FMA4(CA3, XSA_, w3) \
  FMA4(CA4, XSA_, w4) FMA4(CA5, XSA_, w5) FMA4(CA6, XSA_, w6) FMA4(CA7, XSA_, w7) \
  FMA4(CB0, XSB_, w0) FMA4(CB1, XSB_, w1) FMA4(CB2, XSB_, w2) FMA4(CB3, XSB_, w3) \
  FMA4(CB4, XSB_, w4) FMA4(CB5, XSB_, w5) FMA4(CB6, XSB_, w6) FMA4(CB7, XSB_, w7) }

// one x-float4 (4 consecutive k) for both rows
#define QK8(XVA_, XVB_, KB_) \
  QK2(XVA_.x, XVB_.x, KB_)       QK2(XVA_.y, XVB_.y, (KB_) + 1) \
  QK2(XVA_.z, XVB_.z, (KB_) + 2) QK2(XVA_.w, XVB_.w, (KB_) + 3)

// 2 rows/lane, 2 chunks of 32 dims (vs R10's 4x16): same 8-FMA/W-f4
// amortization, but x re-read traffic halved (2 passes not 4) and W s_load
// batches doubled. acc = 16 f4; unroll 4 bounds x-load hoisting.
// Chains bitwise-identical to R10. B == gridDim.x * 512 exactly -> no guards.
__launch_bounds__(256)
__global__ void k_main(const float* __restrict__ item,
                       const float* __restrict__ wct,   // ws+WS_WCT
                       const float* __restrict__ keys,  // ws+WS_KEYS
                       const float* __restrict__ st4,   // ws+WS_ST
                       const float* __restrict__ bq,
                       float* red,                      // ws (atomics)
                       float* __restrict__ slot_weights,
                       float* __restrict__ selected,
                       int B) {
  __shared__ float red_sum[4][S];
  __shared__ int   red_lw[4][S];

  int t = threadIdx.x;
  long rA = (long)blockIdx.x * 512 + t;
  long rB = rA + 256;

  const float4* rowA = (const float4*)(item + rA * D);
  const float4* rowB = (const float4*)(item + rB * D);

  const float4* bq4 = (const float4*)bq;     // uniform
  const float4* kr  = (const float4*)keys;   // uniform

  float SA0 = 0.f, SA1 = 0.f, SA2 = 0.f, SA3 = 0.f;
  float SB0 = 0.f, SB1 = 0.f, SB2 = 0.f, SB3 = 0.f;

  #pragma unroll 1
  for (int c = 0; c < 2; ++c) {
    const float4* wb = (const float4*)wct + c * 512;   // 8KB slab, uniform
    float4 CA0 = bq4[c * 8 + 0], CA1 = bq4[c * 8 + 1];
    float4 CA2 = bq4[c * 8 + 2], CA3 = bq4[c * 8 + 3];
    float4 CA4 = bq4[c * 8 + 4], CA5 = bq4[c * 8 + 5];
    float4 CA6 = bq4[c * 8 + 6], CA7 = bq4[c * 8 + 7];
    float4 CB0 = CA0, CB1 = CA1, CB2 = CA2, CB3 = CA3;
    float4 CB4 = CA4, CB5 = CA5, CB6 = CA6, CB7 = CA7;

    #pragma unroll 4
    for (int kq = 0; kq < 16; ++kq) {
      float4 xa = rowA[kq];
      float4 xb = rowB[kq];
      QK8(xa, xb, kq * 4)
    }

    TANH4(CA0) TANH4(CA1) TANH4(CA2) TANH4(CA3)
    TANH4(CA4) TANH4(CA5) TANH4(CA6) TANH4(CA7)
    TANH4(CB0) TANH4(CB1) TANH4(CB2) TANH4(CB3)
    TANH4(CB4) TANH4(CB5) TANH4(CB6) TANH4(CB7)

    // sims over this chunk's 32 dims (ascending-dim order preserved)
    {
      const float4* k0 = kr + 0 * 16 + c * 8;
      DOT4ACC(SA0, CA0, k0[0]) DOT4ACC(SA0, CA1, k0[1]) DOT4ACC(SA0, CA2, k0[2]) DOT4ACC(SA0, CA3, k0[3])
      DOT4ACC(SA0, CA4, k0[4]) DOT4ACC(SA0, CA5, k0[5]) DOT4ACC(SA0, CA6, k0[6]) DOT4ACC(SA0, CA7, k0[7])
      DOT4ACC(SB0, CB0, k0[0]) DOT4ACC(SB0, CB1, k0[1]) DOT4ACC(SB0, CB2, k0[2]) DOT4ACC(SB0, CB3, k0[3])
      DOT4ACC(SB0, CB4, k0[4]) DOT4ACC(SB0, CB5, k0[5]) DOT4ACC(SB0, CB6, k0[6]) DOT4ACC(SB0, CB7, k0[7])
      const float4* k1 = kr + 1 * 16 + c * 8;
      DOT4ACC(SA1, CA0, k1[0]) DOT4ACC(SA1, CA1, k1[1]) DOT4ACC(SA1, CA2, k1[2]) DOT4ACC(SA1, CA3, k1[3])
      DOT4ACC(SA1, CA4, k1[4]) DOT4ACC(SA1, CA5, k1[5]) DOT4ACC(SA1, CA6, k1[6]) DOT4ACC(SA1, CA7, k1[7])
      DOT4ACC(SB1, CB0, k1[0]) DOT4ACC(SB1, CB1, k1[1]) DOT4ACC(SB1, CB2, k1[2]) DOT4ACC(SB1, CB3, k1[3])
      DOT4ACC(SB1, CB4, k1[4]) DOT4ACC(SB1, CB5, k1[5]) DOT4ACC(SB1, CB6, k1[6]) DOT4ACC(SB1, CB7, k1[7])
      const float4* k2 = kr + 2 * 16 + c * 8;
      DOT4ACC(SA2, CA0, k2[0]) DOT4ACC(SA2, CA1, k2[1]) DOT4ACC(SA2, CA2, k2[2]) DOT4ACC(SA2, CA3, k2[3])
      DOT4ACC(SA2, CA4, k2[4]) DOT4ACC(SA2, CA5, k2[5]) DOT4ACC(SA2, CA6, k2[6]) DOT4ACC(SA2, CA7, k2[7])
      DOT4ACC(SB2, CB0, k2[0]) DOT4ACC(SB2, CB1, k2[1]) DOT4ACC(SB2, CB2, k2[2]) DOT4ACC(SB2, CB3, k2[3])
      DOT4ACC(SB2, CB4, k2[4]) DOT4ACC(SB2, CB5, k2[5]) DOT4ACC(SB2, CB6, k2[6]) DOT4ACC(SB2, CB7, k2[7])
      const float4* k3 = kr + 3 * 16 + c * 8;
      DOT4ACC(SA3, CA0, k3[0]) DOT4ACC(SA3, CA1, k3[1]) DOT4ACC(SA3, CA2, k3[2]) DOT4ACC(SA3, CA3, k3[3])
      DOT4ACC(SA3, CA4, k3[4]) DOT4ACC(SA3, CA5, k3[5]) DOT4ACC(SA3, CA6, k3[6]) DOT4ACC(SA3, CA7, k3[7])
      DOT4ACC(SB3, CB0, k3[0]) DOT4ACC(SB3, CB1, k3[1]) DOT4ACC(SB3, CB2, k3[2]) DOT4ACC(SB3, CB3, k3[3])
      DOT4ACC(SB3, CB4, k3[4]) DOT4ACC(SB3, CB5, k3[5]) DOT4ACC(SB3, CB6, k3[6]) DOT4ACC(SB3, CB7, k3[7])
    }
  }

  float s0 = st4[0], s1 = st4[1], s2 = st4[2], s3 = st4[3];

  float uA[S], uB[S];
  int selA = 0, selB = 0;
  {
    float m = fmaxf(fmaxf(SA0, SA1), fmaxf(SA2, SA3));
    float e0 = expf(SA0 - m), e1 = expf(SA1 - m);
    float e2 = expf(SA2 - m), e3 = expf(SA3 - m);
    float se = e0 + e1 + e2 + e3;
    float w0 = e0 / se, w1 = e1 / se, w2 = e2 / se, w3 = e3 / se;
    *(float4*)(slot_weights + rA * S) = make_float4(w0, w1, w2, w3);
    uA[0] = w0 * s0; uA[1] = w1 * s1; uA[2] = w2 * s2; uA[3] = w3 * s3;
    float us = uA[0] + uA[1] + uA[2] + uA[3];
    uA[0] /= us; uA[1] /= us; uA[2] /= us; uA[3] /= us;
    float best = uA[0];
    if (uA[1] > best) { best = uA[1]; selA = 1; }
    if (uA[2] > best) { best = uA[2]; selA = 2; }
    if (uA[3] > best) { best = uA[3]; selA = 3; }
    selected[rA] = (float)selA;
  }
  {
    float m = fmaxf(fmaxf(SB0, SB1), fmaxf(SB2, SB3));
    float e0 = expf(SB0 - m), e1 = expf(SB1 - m);
    float e2 = expf(SB2 - m), e3 = expf(SB3 - m);
    float se = e0 + e1 + e2 + e3;
    float w0 = e0 / se, w1 = e1 / se, w2 = e2 / se, w3 = e3 / se;
    *(float4*)(slot_weights + rB * S) = make_float4(w0, w1, w2, w3);
    uB[0] = w0 * s0; uB[1] = w1 * s1; uB[2] = w2 * s2; uB[3] = w3 * s3;
    float us = uB[0] + uB[1] + uB[2] + uB[3];
    uB[0] /= us; uB[1] /= us; uB[2] /= us; uB[3] /= us;
    float best = uB[0];
    if (uB[1] > best) { best = uB[1]; selB = 1; }
    if (uB[2] > best) { best = uB[2]; selB = 2; }
    if (uB[3] > best) { best = uB[3]; selB = 3; }
    selected[rB] = (float)selB;
  }

  // ---- block reduction: uw sums (add) and last-writer (max) ----
  float r[S]; int l[S];
  #pragma unroll
  for (int s = 0; s < S; ++s) {
    r[s] = uA[s] + uB[s];
    l[s] = (selB == s) ? (int)rB : ((selA == s) ? (int)rA : -1);  // rB > rA
  }
  #pragma unroll
  for (int off = 32; off > 0; off >>= 1) {
    #pragma unroll
    for (int s = 0; s < S; ++s) {
      r[s] += __shfl_down(r[s], off);
      int m = __shfl_down(l[s], off);
      l[s] = l[s] > m ? l[s] : m;
    }
  }
  int lane = t & 63, wid = t >> 6;
  if (lane == 0) {
    #pragma unroll
    for (int s = 0; s < S; ++s) { red_sum[wid][s] = r[s]; red_lw[wid][s] = l[s]; }
  }
  __syncthreads();
  if (t < S) {
    float tot = red_sum[0][t] + red_sum[1][t] + red_sum[2][t] + red_sum[3][t];
    atomicAdd(&red[WS_SUMS + t], tot);
    int lm = red_lw[0][t];
    if (red_lw[1][t] > lm) lm = red_lw[1][t];
    if (red_lw[2][t] > lm) lm = red_lw[2][t];
    if (red_lw[3][t] > lm) lm = red_lw[3][t];
    atomicMax((int*)red + WS_LW + t, lm);
  }
}

__global__ void k_final(const float* __restrict__ item,
                        const float* __restrict__ slots,
                        const float* __restrict__ usage,
                        const float* __restrict__ Wv,
                        const float* __restrict__ bv,
                        float* ws,
                        float* __restrict__ out_ns,
                        float* __restrict__ out_nu,
                        int B) {
  int d = threadIdx.x;  // 64 threads
  __shared__ float mean[D];
  const int* lw = (const int*)ws + WS_LW;
  float nsv[S];
  for (int s = 0; s < S; ++s) {
    int w = lw[s];
    float v = (w >= 0) ? item[(size_t)w * D + d] : slots[s * D + d];
    nsv[s] = v;
    out_ns[s * D + d] = v;
  }
  mean[d] = (nsv[0] + nsv[1] + nsv[2] + nsv[3]) * 0.25f;
  __syncthreads();
  float acc = bv[d];
  for (int k = 0; k < D; ++k) acc = fmaf(mean[k], Wv[d * D + k], acc);
  ws[WS_OUT1 + d] = tanhf(acc);
  if (d < S) out_nu[d] = usage[d] * 0.9f + ws[WS_SUMS + d] / (float)B;
}

__global__ void k_bcast(const float* __restrict__ ws,
                        float4* __restrict__ out, long n4) {
  __shared__ float4 o4[16];
  if (threadIdx.x < 16) o4[threadIdx.x] = ((const float4*)(ws + WS_OUT1))[threadIdx.x];
  __syncthreads();
  long i = (long)blockIdx.x * blockDim.x + threadIdx.x;
  long stride = (long)gridDim.x * blockDim.x;
  for (; i < n4; i += stride) out[i] = o4[i & 15];
}

extern "C" void kernel_launch(void* const* d_in, const int* in_sizes, int n_in,
                              void* d_out, int out_size, void* d_ws, size_t ws_size,
                              hipStream_t stream) {
  const float* item  = (const float*)d_in[0];
  const float* slots = (const float*)d_in[1];
  const float* ss    = (const float*)d_in[2];
  const float* usage = (const float*)d_in[3];
  const float* Wq    = (const float*)d_in[4];
  const float* bq    = (const float*)d_in[5];
  const float* Wk    = (const float*)d_in[6];
  const float* bk    = (const float*)d_in[7];
  const float* Wv    = (const float*)d_in[8];
  const float* bv    = (const float*)d_in[9];
  int B = in_sizes[0] / D;
  float* ws = (float*)d_ws;

  float* out_output       = (float*)d_out;
  float* out_new_slots    = out_output + (size_t)B * D;
  float* out_new_usage    = out_new_slots + S * D;
  float* out_selected     = out_new_usage + S;
  float* out_slot_weights = out_selected + B;

  k_prep<<<1, 64, 0, stream>>>(slots, ss, Wk, bk, Wq, ws);
  k_main<<<B / 512, 256, 0, stream>>>(
      item, ws + WS_WCT, ws + WS_KEYS, ws + WS_ST, bq, ws,
      out_slot_weights, out_selected, B);
  k_final<<<1, 64, 0, stream>>>(item, slots, usage, Wv, bv, ws,
                                out_new_slots, out_new_usage, B);
  long n4 = (long)B * D / 4;
  k_bcast<<<2048, 256, 0, stream>>>(ws, (float4*)out_output, n4);
}